// Round 13
// baseline (158.424 us; speedup 1.0000x reference)
//
#include <hip/hip_runtime.h>
#include <hip/hip_bf16.h>
#include <math.h>

#define BATCH 64
#define DIM 1024
#define NROW (BATCH * DIM)        // 65536 rows of C
// d_out layout (floats): h[65536] | C_new[67108864] | n_new[65536] | m_new[65536]
#define OFF_H 0
#define OFF_C 65536
#define OFF_N (65536 + 67108864)
#define OFF_M (OFF_N + 65536)

typedef float f4     __attribute__((ext_vector_type(4)));
typedef float f32x4  __attribute__((ext_vector_type(4)));   // MFMA C/D frag
typedef short bf16x8 __attribute__((ext_vector_type(8)));   // MFMA A/B frag (8 bf16)

// ws layout (floats): pre[6][NROW], gate order 0:q 1:k 2:v 3:i 4:f 5:o

__device__ inline short f2bf(float v) {
    __hip_bfloat16 h = __float2bfloat16(v);   // RNE convert
    short s;
    __builtin_memcpy(&s, &h, 2);
    return s;
}

__device__ inline bf16x8 load_bf8(const float* __restrict__ p) {
    f4 a = *reinterpret_cast<const f4*>(p);
    f4 b = *reinterpret_cast<const f4*>(p + 4);
    bf16x8 r;
    r[0] = f2bf(a.x); r[1] = f2bf(a.y); r[2] = f2bf(a.z); r[3] = f2bf(a.w);
    r[4] = f2bf(b.x); r[5] = f2bf(b.y); r[6] = f2bf(b.z); r[7] = f2bf(b.w);
    return r;
}

__device__ inline int   biti(float f) { int i;   __builtin_memcpy(&i, &f, 4); return i; }
__device__ inline float bitf(int i)   { float f; __builtin_memcpy(&f, &i, 4); return f; }

// Wave-64 sum via DPP (row_shr x4 + row_bcast15 + row_bcast31), wave-uniform
// result from readlane 63. ~6 VALU-latency deps, no LDS.
__device__ inline float wave_sum64_dpp(float x) {
    int t;
    t = __builtin_amdgcn_update_dpp(0, biti(x), 0x111, 0xF, 0xF, true); x += bitf(t);
    t = __builtin_amdgcn_update_dpp(0, biti(x), 0x112, 0xF, 0xF, true); x += bitf(t);
    t = __builtin_amdgcn_update_dpp(0, biti(x), 0x114, 0xF, 0xF, true); x += bitf(t);
    t = __builtin_amdgcn_update_dpp(0, biti(x), 0x118, 0xF, 0xF, true); x += bitf(t);
    t = __builtin_amdgcn_update_dpp(0, biti(x), 0x142, 0xA, 0xF, true); x += bitf(t);
    t = __builtin_amdgcn_update_dpp(0, biti(x), 0x143, 0xC, 0xF, true); x += bitf(t);
    return bitf(__builtin_amdgcn_readlane(biti(x), 63));
}

// ---------------------------------------------------------------------------
// Kernel 1: six GEMMs via bf16 MFMA (unchanged from R4).
// ---------------------------------------------------------------------------
__global__ __launch_bounds__(256) void gemm6_mfma(
    const float* __restrict__ x,
    const float* __restrict__ Wq, const float* __restrict__ bq,
    const float* __restrict__ Wk, const float* __restrict__ bk,
    const float* __restrict__ Wv, const float* __restrict__ bv,
    const float* __restrict__ Wi, const float* __restrict__ bi,
    const float* __restrict__ Wf, const float* __restrict__ bf_,
    const float* __restrict__ Wo, const float* __restrict__ bo,
    float* __restrict__ pre)
{
    const int bx = blockIdx.x;
    const int g  = bx >> 6;             // gate
    const int j0 = (bx & 63) << 4;      // 16-col tile
    const float* W; const float* bias;
    switch (g) {
        case 0: W = Wq; bias = bq; break;
        case 1: W = Wk; bias = bk; break;
        case 2: W = Wv; bias = bv; break;
        case 3: W = Wi; bias = bi; break;
        case 4: W = Wf; bias = bf_; break;
        default: W = Wo; bias = bo; break;
    }

    const int wave = threadIdx.x >> 6;
    const int lane = threadIdx.x & 63;
    const int l15  = lane & 15;
    const int kq   = lane >> 4;         // 0..3

    const float* xrow = x + (size_t)(wave * 16 + l15) * DIM + kq * 8;
    const float* wrow = W + (size_t)(j0 + l15) * DIM + kq * 8;

    f32x4 acc0 = {0.f, 0.f, 0.f, 0.f};
    f32x4 acc1 = {0.f, 0.f, 0.f, 0.f};
    #pragma unroll 4
    for (int kt = 0; kt < 32; kt += 2) {
        bf16x8 a0 = load_bf8(xrow + kt * 32);
        bf16x8 b0 = load_bf8(wrow + kt * 32);
        bf16x8 a1 = load_bf8(xrow + kt * 32 + 32);
        bf16x8 b1 = load_bf8(wrow + kt * 32 + 32);
        acc0 = __builtin_amdgcn_mfma_f32_16x16x32_bf16(a0, b0, acc0, 0, 0, 0);
        acc1 = __builtin_amdgcn_mfma_f32_16x16x32_bf16(a1, b1, acc1, 0, 0, 0);
    }
    acc0 += acc1;

    const float bv_ = bias[j0 + l15];           // D col = lane&15
    float* dst = pre + (size_t)g * NROW + (size_t)(wave * 16 + kq * 4) * DIM + j0 + l15;
    #pragma unroll
    for (int r = 0; r < 4; ++r)
        dst[(size_t)r * DIM] = acc0[r] + bv_;   // D row = kq*4 + r
}

// ---------------------------------------------------------------------------
// Kernel 2 v9: register-slim TWO-PASS stream, occupancy-first.
// v5 semantics (nt-load, plain store, deferred reduces) but each row's 4 KB
// is split into two column-half passes over the 8 rows, so only 2 k-frags +
// 2 q-frags + 2 c-frags are live at a time (~44 VGPR). __launch_bounds__
// (256,8) pins 8 waves/EU. kqdot via transient prologue regs.
// ---------------------------------------------------------------------------
#define RPB 32   // rows per block
__global__ __launch_bounds__(256, 8) void cupdate9(
    const float* __restrict__ C,
    const float* __restrict__ n_in, const float* __restrict__ m_in,
    const float* __restrict__ ws,
    float* __restrict__ out)
{
    __shared__ float kq[2][DIM];          // k_raw, q  (8 KB)
    __shared__ float s_fex[RPB], s_ksc[RPB], s_so[RPB];

    const int blk  = blockIdx.x;          // 0..2047
    const int b    = blk >> 5;            // batch
    const int rg   = blk & 31;            // row-group
    const int tid  = threadIdx.x;
    const int w    = tid >> 6;
    const int lane = tid & 63;

    // stage k (raw pre_k) and q
    reinterpret_cast<f4*>(kq[0])[tid] = reinterpret_cast<const f4*>(ws + 1 * NROW + b * DIM)[tid];
    reinterpret_cast<f4*>(kq[1])[tid] = reinterpret_cast<const f4*>(ws + 0 * NROW + b * DIM)[tid];

    // per-row gate scalars + n_new/m_new (32 rows, threads 0..31)
    if (tid < RPB) {
        const int row = b * DIM + rg * RPB + tid;
        const float ip  = ws[3 * NROW + row];
        const float fp_ = ws[4 * NROW + row];
        const float op  = ws[5 * NROW + row];
        const float vp  = ws[2 * NROW + row];
        const float mo  = m_in[row];
        const float mn  = fmaxf(fp_ + mo, ip);
        const float iex = expf(ip - mn);
        const float fex = expf(fp_ + mo - mn);
        s_fex[tid] = fex;
        s_ksc[tid] = iex * vp * 0.03125f;
        s_so[tid]  = 1.f / (1.f + expf(-op));
        out[OFF_N + row] = fex * n_in[row] + iex * ws[1 * NROW + row] * 0.03125f;
        out[OFF_M + row] = mn;
    }
    __syncthreads();

    const f4* kl = reinterpret_cast<const f4*>(kq[0]);
    const f4* ql = reinterpret_cast<const f4*>(kq[1]);

    // batch-level dot(k_raw, q): transient regs, freed before the stream
    float kqdot;
    {
        f4 pp = kl[lane] * ql[lane] + kl[lane + 64] * ql[lane + 64]
              + kl[lane + 128] * ql[lane + 128] + kl[lane + 192] * ql[lane + 192];
        kqdot = wave_sum64_dpp(pp.x + pp.y + pp.z + pp.w);
    }

    const int grow0 = b * DIM + rg * RPB + w * 8;   // wave's first row
    const f4* C4 = reinterpret_cast<const f4*>(C) + (size_t)grow0 * 256;
    f4*       O4 = reinterpret_cast<f4*>(out + OFF_C) + (size_t)grow0 * 256;

    float dacc[8];
    #pragma unroll
    for (int rr = 0; rr < 8; ++rr) dacc[rr] = 0.f;

    // ---- pass A: column f4-indices [0,128) ----
    {
        f4 ka0 = kl[lane], ka1 = kl[lane + 64];
        f4 qa0 = ql[lane], qa1 = ql[lane + 64];
        #pragma unroll
        for (int rr = 0; rr < 8; ++rr) {
            const float fex = s_fex[w * 8 + rr];
            const float ksc = s_ksc[w * 8 + rr];
            const int base = rr * 256 + lane;
            f4 c0 = __builtin_nontemporal_load(&C4[base]);
            f4 c1 = __builtin_nontemporal_load(&C4[base + 64]);
            O4[base]      = fex * c0 + ksc * ka0;
            O4[base + 64] = fex * c1 + ksc * ka1;
            f4 d = c0 * qa0 + c1 * qa1;
            dacc[rr] += d.x + d.y + d.z + d.w;
        }
    }
    // ---- pass B: column f4-indices [128,256) ----
    {
        f4 kb0 = kl[lane + 128], kb1 = kl[lane + 192];
        f4 qb0 = ql[lane + 128], qb1 = ql[lane + 192];
        #pragma unroll
        for (int rr = 0; rr < 8; ++rr) {
            const float fex = s_fex[w * 8 + rr];
            const float ksc = s_ksc[w * 8 + rr];
            const int base = rr * 256 + lane;
            f4 c2 = __builtin_nontemporal_load(&C4[base + 128]);
            f4 c3 = __builtin_nontemporal_load(&C4[base + 192]);
            O4[base + 128] = fex * c2 + ksc * kb0;
            O4[base + 192] = fex * c3 + ksc * kb1;
            f4 d = c2 * qb0 + c3 * qb1;
            dacc[rr] += d.x + d.y + d.z + d.w;
        }
    }

    // 8 independent reduces (ILP) + h stores, once per wave
    float dC[8];
    #pragma unroll
    for (int rr = 0; rr < 8; ++rr) dC[rr] = wave_sum64_dpp(dacc[rr]);
    if (lane == 0) {
        #pragma unroll
        for (int rr = 0; rr < 8; ++rr) {
            out[OFF_H + grow0 + rr] =
                s_so[w * 8 + rr] * (s_fex[w * 8 + rr] * dC[rr] + s_ksc[w * 8 + rr] * kqdot);
        }
    }
}

extern "C" void kernel_launch(void* const* d_in, const int* in_sizes, int n_in,
                              void* d_out, int out_size, void* d_ws, size_t ws_size,
                              hipStream_t stream) {
    const float* x = (const float*)d_in[0];
    const float* C = (const float*)d_in[1];
    const float* n = (const float*)d_in[2];
    const float* m = (const float*)d_in[3];
    float* ws  = (float*)d_ws;    // needs 6*65536*4 = 1.5 MB
    float* out = (float*)d_out;

    gemm6_mfma<<<384, 256, 0, stream>>>(
        x,
        (const float*)d_in[4],  (const float*)d_in[5],
        (const float*)d_in[6],  (const float*)d_in[7],
        (const float*)d_in[8],  (const float*)d_in[9],
        (const float*)d_in[10], (const float*)d_in[11],
        (const float*)d_in[12], (const float*)d_in[13],
        (const float*)d_in[14], (const float*)d_in[15],
        ws);
    cupdate9<<<2048, 256, 0, stream>>>(C, n, m, ws, out);
}

// Round 14
// 121.851 us; speedup vs baseline: 1.3001x; 1.3001x over previous
//
#include <hip/hip_runtime.h>
#include <hip/hip_bf16.h>
#include <math.h>

#define BATCH 64
#define DIM 1024
#define NROW (BATCH * DIM)        // 65536 rows of C
// d_out layout (floats): h[65536] | C_new[67108864] | n_new[65536] | m_new[65536]
#define OFF_H 0
#define OFF_C 65536
#define OFF_N (65536 + 67108864)
#define OFF_M (OFF_N + 65536)

typedef float f4     __attribute__((ext_vector_type(4)));
typedef float f32x4  __attribute__((ext_vector_type(4)));   // MFMA C/D frag
typedef short bf16x8 __attribute__((ext_vector_type(8)));   // MFMA A/B frag (8 bf16)

// ws layout (floats): pre[6][NROW], gate order 0:q 1:k 2:v 3:i 4:f 5:o

__device__ inline short f2bf(float v) {
    __hip_bfloat16 h = __float2bfloat16(v);   // RNE convert
    short s;
    __builtin_memcpy(&s, &h, 2);
    return s;
}

__device__ inline bf16x8 load_bf8(const float* __restrict__ p) {
    f4 a = *reinterpret_cast<const f4*>(p);
    f4 b = *reinterpret_cast<const f4*>(p + 4);
    bf16x8 r;
    r[0] = f2bf(a.x); r[1] = f2bf(a.y); r[2] = f2bf(a.z); r[3] = f2bf(a.w);
    r[4] = f2bf(b.x); r[5] = f2bf(b.y); r[6] = f2bf(b.z); r[7] = f2bf(b.w);
    return r;
}

__device__ inline int   biti(float f) { int i;   __builtin_memcpy(&i, &f, 4); return i; }
__device__ inline float bitf(int i)   { float f; __builtin_memcpy(&f, &i, 4); return f; }

// Wave-64 sum via DPP (row_shr x4 + row_bcast15 + row_bcast31), wave-uniform
// result from readlane 63. ~6 VALU-latency deps, no LDS.
__device__ inline float wave_sum64_dpp(float x) {
    int t;
    t = __builtin_amdgcn_update_dpp(0, biti(x), 0x111, 0xF, 0xF, true); x += bitf(t);
    t = __builtin_amdgcn_update_dpp(0, biti(x), 0x112, 0xF, 0xF, true); x += bitf(t);
    t = __builtin_amdgcn_update_dpp(0, biti(x), 0x114, 0xF, 0xF, true); x += bitf(t);
    t = __builtin_amdgcn_update_dpp(0, biti(x), 0x118, 0xF, 0xF, true); x += bitf(t);
    t = __builtin_amdgcn_update_dpp(0, biti(x), 0x142, 0xA, 0xF, true); x += bitf(t);
    t = __builtin_amdgcn_update_dpp(0, biti(x), 0x143, 0xC, 0xF, true); x += bitf(t);
    return bitf(__builtin_amdgcn_readlane(biti(x), 63));
}

// ---------------------------------------------------------------------------
// Kernel 1: six GEMMs via bf16 MFMA (unchanged from R4).
// ---------------------------------------------------------------------------
__global__ __launch_bounds__(256) void gemm6_mfma(
    const float* __restrict__ x,
    const float* __restrict__ Wq, const float* __restrict__ bq,
    const float* __restrict__ Wk, const float* __restrict__ bk,
    const float* __restrict__ Wv, const float* __restrict__ bv,
    const float* __restrict__ Wi, const float* __restrict__ bi,
    const float* __restrict__ Wf, const float* __restrict__ bf_,
    const float* __restrict__ Wo, const float* __restrict__ bo,
    float* __restrict__ pre)
{
    const int bx = blockIdx.x;
    const int g  = bx >> 6;             // gate
    const int j0 = (bx & 63) << 4;      // 16-col tile
    const float* W; const float* bias;
    switch (g) {
        case 0: W = Wq; bias = bq; break;
        case 1: W = Wk; bias = bk; break;
        case 2: W = Wv; bias = bv; break;
        case 3: W = Wi; bias = bi; break;
        case 4: W = Wf; bias = bf_; break;
        default: W = Wo; bias = bo; break;
    }

    const int wave = threadIdx.x >> 6;
    const int lane = threadIdx.x & 63;
    const int l15  = lane & 15;
    const int kq   = lane >> 4;         // 0..3

    const float* xrow = x + (size_t)(wave * 16 + l15) * DIM + kq * 8;
    const float* wrow = W + (size_t)(j0 + l15) * DIM + kq * 8;

    f32x4 acc0 = {0.f, 0.f, 0.f, 0.f};
    f32x4 acc1 = {0.f, 0.f, 0.f, 0.f};
    #pragma unroll 4
    for (int kt = 0; kt < 32; kt += 2) {
        bf16x8 a0 = load_bf8(xrow + kt * 32);
        bf16x8 b0 = load_bf8(wrow + kt * 32);
        bf16x8 a1 = load_bf8(xrow + kt * 32 + 32);
        bf16x8 b1 = load_bf8(wrow + kt * 32 + 32);
        acc0 = __builtin_amdgcn_mfma_f32_16x16x32_bf16(a0, b0, acc0, 0, 0, 0);
        acc1 = __builtin_amdgcn_mfma_f32_16x16x32_bf16(a1, b1, acc1, 0, 0, 0);
    }
    acc0 += acc1;

    const float bv_ = bias[j0 + l15];           // D col = lane&15
    float* dst = pre + (size_t)g * NROW + (size_t)(wave * 16 + kq * 4) * DIM + j0 + l15;
    #pragma unroll
    for (int r = 0; r < 4; ++r)
        dst[(size_t)r * DIM] = acc0[r] + bv_;   // D row = kq*4 + r
}

// ---------------------------------------------------------------------------
// Kernel 2 v10: minimal-register cooperative-row stream (occupancy test).
// 2048 blocks (64 b x 32 rows) x 256 thr. The 4 waves each own a QUARTER of
// every row: lane holds ONE f4 of k and q. Per row-step per wave:
// {1 nt-load, 1 plain store, 2 f4-FMA, scalar dacc}. Live set ~35-45 VGPR ->
// __launch_bounds__(256,8) = 8 waves/SIMD. Streaming shape unchanged:
// 1 KB contiguous per instruction, 4 waves tile each 4 KB row, block sweeps
// 128 KB linearly. Per-row dot = 4 cross-wave partials combined in a tiny
// LDS epilogue per 8-row group (outside the stream).
// ---------------------------------------------------------------------------
#define RPB 32   // rows per block
__global__ __launch_bounds__(256, 8) void cupdate10(
    const float* __restrict__ C,
    const float* __restrict__ n_in, const float* __restrict__ m_in,
    const float* __restrict__ ws,
    float* __restrict__ out)
{
    __shared__ float kq[2][DIM];                  // k_raw, q  (8 KB)
    __shared__ float s_fex[RPB], s_ksc[RPB], s_so[RPB];
    __shared__ float s_part[4][RPB];              // per-wave dot partials
    __shared__ float s_kqp[4];                    // per-wave kqdot partials

    const int blk  = blockIdx.x;          // 0..2047
    const int b    = blk >> 5;            // batch
    const int rg   = blk & 31;            // row-group
    const int tid  = threadIdx.x;
    const int w    = tid >> 6;
    const int lane = tid & 63;

    // stage k (raw pre_k) and q: 256 f4 each, one f4 per thread
    reinterpret_cast<f4*>(kq[0])[tid] = reinterpret_cast<const f4*>(ws + 1 * NROW + b * DIM)[tid];
    reinterpret_cast<f4*>(kq[1])[tid] = reinterpret_cast<const f4*>(ws + 0 * NROW + b * DIM)[tid];

    // per-row gate scalars + n_new/m_new (32 rows, threads 0..31)
    if (tid < RPB) {
        const int row = b * DIM + rg * RPB + tid;
        const float ip  = ws[3 * NROW + row];
        const float fp_ = ws[4 * NROW + row];
        const float op  = ws[5 * NROW + row];
        const float vp  = ws[2 * NROW + row];
        const float mo  = m_in[row];
        const float mn  = fmaxf(fp_ + mo, ip);
        const float iex = expf(ip - mn);
        const float fex = expf(fp_ + mo - mn);
        s_fex[tid] = fex;
        s_ksc[tid] = iex * vp * 0.03125f;
        s_so[tid]  = 1.f / (1.f + expf(-op));
        out[OFF_N + row] = fex * n_in[row] + iex * ws[1 * NROW + row] * 0.03125f;
        out[OFF_M + row] = mn;
    }
    __syncthreads();

    // each lane's single k/q f4 (quarter-row ownership: f4 index w*64+lane)
    const f4 kf = reinterpret_cast<const f4*>(kq[0])[w * 64 + lane];
    const f4 qf = reinterpret_cast<const f4*>(kq[1])[w * 64 + lane];

    // kqdot: per-wave quarter partial -> LDS -> summed by all
    {
        f4 pp = kf * qf;
        float p = wave_sum64_dpp(pp.x + pp.y + pp.z + pp.w);
        if (lane == 0) s_kqp[w] = p;
    }
    __syncthreads();
    const float kqdot = s_kqp[0] + s_kqp[1] + s_kqp[2] + s_kqp[3];

    const int grow0 = b * DIM + rg * RPB;         // block's first row
    const f4* Cb = reinterpret_cast<const f4*>(C) + (size_t)grow0 * 256;
    f4*       Ob = reinterpret_cast<f4*>(out + OFF_C) + (size_t)grow0 * 256;
    const int coff = w * 64 + lane;               // this thread's f4 within a row

    // 4 groups of 8 rows; dacc[8] only
    #pragma unroll
    for (int g8 = 0; g8 < 4; ++g8) {
        float dacc[8];
        #pragma unroll
        for (int rr = 0; rr < 8; ++rr) {
            const int r = g8 * 8 + rr;
            const float fex = s_fex[r];
            const float ksc = s_ksc[r];
            const int idx = r * 256 + coff;
            f4 c = __builtin_nontemporal_load(&Cb[idx]);
            Ob[idx] = fex * c + ksc * kf;
            f4 d = c * qf;
            dacc[rr] = d.x + d.y + d.z + d.w;
        }
        #pragma unroll
        for (int rr = 0; rr < 8; ++rr) {
            float p = wave_sum64_dpp(dacc[rr]);
            if (lane == 0) s_part[w][g8 * 8 + rr] = p;
        }
    }
    __syncthreads();

    // h epilogue: threads 0..31 combine the 4 wave partials per row
    if (tid < RPB) {
        const float dC = s_part[0][tid] + s_part[1][tid] + s_part[2][tid] + s_part[3][tid];
        out[OFF_H + grow0 + tid] = s_so[tid] * (s_fex[tid] * dC + s_ksc[tid] * kqdot);
    }
}

extern "C" void kernel_launch(void* const* d_in, const int* in_sizes, int n_in,
                              void* d_out, int out_size, void* d_ws, size_t ws_size,
                              hipStream_t stream) {
    const float* x = (const float*)d_in[0];
    const float* C = (const float*)d_in[1];
    const float* n = (const float*)d_in[2];
    const float* m = (const float*)d_in[3];
    float* ws  = (float*)d_ws;    // needs 6*65536*4 = 1.5 MB
    float* out = (float*)d_out;

    gemm6_mfma<<<384, 256, 0, stream>>>(
        x,
        (const float*)d_in[4],  (const float*)d_in[5],
        (const float*)d_in[6],  (const float*)d_in[7],
        (const float*)d_in[8],  (const float*)d_in[9],
        (const float*)d_in[10], (const float*)d_in[11],
        (const float*)d_in[12], (const float*)d_in[13],
        (const float*)d_in[14], (const float*)d_in[15],
        ws);
    cupdate10<<<2048, 256, 0, stream>>>(C, n, m, ws, out);
}

// Round 15
// 121.517 us; speedup vs baseline: 1.3037x; 1.0027x over previous
//
#include <hip/hip_runtime.h>
#include <hip/hip_bf16.h>
#include <math.h>

#define BATCH 64
#define DIM 1024
#define NROW (BATCH * DIM)        // 65536 rows of C
// d_out layout (floats): h[65536] | C_new[67108864] | n_new[65536] | m_new[65536]
#define OFF_H 0
#define OFF_C 65536
#define OFF_N (65536 + 67108864)
#define OFF_M (OFF_N + 65536)

typedef float f4     __attribute__((ext_vector_type(4)));
typedef float f32x4  __attribute__((ext_vector_type(4)));   // MFMA C/D frag
typedef short bf16x8 __attribute__((ext_vector_type(8)));   // MFMA A/B frag (8 bf16)

// ws layout (floats): pre[6][NROW], gate order 0:q 1:k 2:v 3:i 4:f 5:o

__device__ inline short f2bf(float v) {
    __hip_bfloat16 h = __float2bfloat16(v);   // RNE convert
    short s;
    __builtin_memcpy(&s, &h, 2);
    return s;
}

__device__ inline bf16x8 load_bf8(const float* __restrict__ p) {
    f4 a = *reinterpret_cast<const f4*>(p);
    f4 b = *reinterpret_cast<const f4*>(p + 4);
    bf16x8 r;
    r[0] = f2bf(a.x); r[1] = f2bf(a.y); r[2] = f2bf(a.z); r[3] = f2bf(a.w);
    r[4] = f2bf(b.x); r[5] = f2bf(b.y); r[6] = f2bf(b.z); r[7] = f2bf(b.w);
    return r;
}

__device__ inline int   biti(float f) { int i;   __builtin_memcpy(&i, &f, 4); return i; }
__device__ inline float bitf(int i)   { float f; __builtin_memcpy(&f, &i, 4); return f; }

// Wave-64 sum via DPP (row_shr x4 + row_bcast15 + row_bcast31), wave-uniform
// result from readlane 63. ~6 VALU-latency deps, no LDS.
__device__ inline float wave_sum64_dpp(float x) {
    int t;
    t = __builtin_amdgcn_update_dpp(0, biti(x), 0x111, 0xF, 0xF, true); x += bitf(t);
    t = __builtin_amdgcn_update_dpp(0, biti(x), 0x112, 0xF, 0xF, true); x += bitf(t);
    t = __builtin_amdgcn_update_dpp(0, biti(x), 0x114, 0xF, 0xF, true); x += bitf(t);
    t = __builtin_amdgcn_update_dpp(0, biti(x), 0x118, 0xF, 0xF, true); x += bitf(t);
    t = __builtin_amdgcn_update_dpp(0, biti(x), 0x142, 0xA, 0xF, true); x += bitf(t);
    t = __builtin_amdgcn_update_dpp(0, biti(x), 0x143, 0xC, 0xF, true); x += bitf(t);
    return bitf(__builtin_amdgcn_readlane(biti(x), 63));
}

// ---------------------------------------------------------------------------
// Kernel 1: six GEMMs via bf16 MFMA (unchanged from R4).
// ---------------------------------------------------------------------------
__global__ __launch_bounds__(256) void gemm6_mfma(
    const float* __restrict__ x,
    const float* __restrict__ Wq, const float* __restrict__ bq,
    const float* __restrict__ Wk, const float* __restrict__ bk,
    const float* __restrict__ Wv, const float* __restrict__ bv,
    const float* __restrict__ Wi, const float* __restrict__ bi,
    const float* __restrict__ Wf, const float* __restrict__ bf_,
    const float* __restrict__ Wo, const float* __restrict__ bo,
    float* __restrict__ pre)
{
    const int bx = blockIdx.x;
    const int g  = bx >> 6;             // gate
    const int j0 = (bx & 63) << 4;      // 16-col tile
    const float* W; const float* bias;
    switch (g) {
        case 0: W = Wq; bias = bq; break;
        case 1: W = Wk; bias = bk; break;
        case 2: W = Wv; bias = bv; break;
        case 3: W = Wi; bias = bi; break;
        case 4: W = Wf; bias = bf_; break;
        default: W = Wo; bias = bo; break;
    }

    const int wave = threadIdx.x >> 6;
    const int lane = threadIdx.x & 63;
    const int l15  = lane & 15;
    const int kq   = lane >> 4;         // 0..3

    const float* xrow = x + (size_t)(wave * 16 + l15) * DIM + kq * 8;
    const float* wrow = W + (size_t)(j0 + l15) * DIM + kq * 8;

    f32x4 acc0 = {0.f, 0.f, 0.f, 0.f};
    f32x4 acc1 = {0.f, 0.f, 0.f, 0.f};
    #pragma unroll 4
    for (int kt = 0; kt < 32; kt += 2) {
        bf16x8 a0 = load_bf8(xrow + kt * 32);
        bf16x8 b0 = load_bf8(wrow + kt * 32);
        bf16x8 a1 = load_bf8(xrow + kt * 32 + 32);
        bf16x8 b1 = load_bf8(wrow + kt * 32 + 32);
        acc0 = __builtin_amdgcn_mfma_f32_16x16x32_bf16(a0, b0, acc0, 0, 0, 0);
        acc1 = __builtin_amdgcn_mfma_f32_16x16x32_bf16(a1, b1, acc1, 0, 0, 0);
    }
    acc0 += acc1;

    const float bv_ = bias[j0 + l15];           // D col = lane&15
    float* dst = pre + (size_t)g * NROW + (size_t)(wave * 16 + kq * 4) * DIM + j0 + l15;
    #pragma unroll
    for (int r = 0; r < 4; ++r)
        dst[(size_t)r * DIM] = acc0[r] + bv_;   // D row = kq*4 + r
}

// ---------------------------------------------------------------------------
// Kernel 2 v11 = v5 config (nt-load, plain store, reg k/q, deferred DPP)
// with RPB 32 -> 64: 1024 blocks (64 b x 16 rowgroups), wave owns 16 rows.
// Halves k/q staging traffic + prologue count; reduce tail amortized 2x.
// ---------------------------------------------------------------------------
#define RPB 64   // rows per block
__global__ __launch_bounds__(256) void cupdate11(
    const float* __restrict__ C,
    const float* __restrict__ n_in, const float* __restrict__ m_in,
    const float* __restrict__ ws,
    float* __restrict__ out)
{
    __shared__ float kq[2][DIM];          // k_raw, q  (8 KB)
    __shared__ float s_fex[RPB], s_ksc[RPB], s_so[RPB];

    const int blk  = blockIdx.x;          // 0..1023
    const int b    = blk >> 4;            // batch
    const int rg   = blk & 15;            // row-group
    const int tid  = threadIdx.x;
    const int w    = tid >> 6;
    const int lane = tid & 63;

    // stage k (raw pre_k) and q: 256 f4 each, one f4 per thread
    reinterpret_cast<f4*>(kq[0])[tid] = reinterpret_cast<const f4*>(ws + 1 * NROW + b * DIM)[tid];
    reinterpret_cast<f4*>(kq[1])[tid] = reinterpret_cast<const f4*>(ws + 0 * NROW + b * DIM)[tid];

    // per-row gate scalars + n_new/m_new (64 rows, threads 0..63)
    if (tid < RPB) {
        const int row = b * DIM + rg * RPB + tid;
        const float ip  = ws[3 * NROW + row];
        const float fp_ = ws[4 * NROW + row];
        const float op  = ws[5 * NROW + row];
        const float vp  = ws[2 * NROW + row];
        const float mo  = m_in[row];
        const float mn  = fmaxf(fp_ + mo, ip);
        const float iex = expf(ip - mn);
        const float fex = expf(fp_ + mo - mn);
        s_fex[tid] = fex;
        s_ksc[tid] = iex * vp * 0.03125f;
        s_so[tid]  = 1.f / (1.f + expf(-op));
        out[OFF_N + row] = fex * n_in[row] + iex * ws[1 * NROW + row] * 0.03125f;
        out[OFF_M + row] = mn;
    }
    __syncthreads();

    // hoist k/q fragments to registers (row-invariant)
    const f4* kl = reinterpret_cast<const f4*>(kq[0]);
    const f4* ql = reinterpret_cast<const f4*>(kq[1]);
    f4 k0 = kl[lane],       k1 = kl[lane + 64],
       k2 = kl[lane + 128], k3 = kl[lane + 192];
    f4 q0 = ql[lane],       q1 = ql[lane + 64],
       q2 = ql[lane + 128], q3 = ql[lane + 192];

    // batch-level dot(k_raw, q): once per wave (64 lanes cover the full row)
    f4 pp = k0 * q0 + k1 * q1 + k2 * q2 + k3 * q3;
    const float kqdot = wave_sum64_dpp(pp.x + pp.y + pp.z + pp.w);

    const int grow0 = b * DIM + rg * RPB + w * 16;   // wave's first row
    const f4* C4 = reinterpret_cast<const f4*>(C) + (size_t)grow0 * 256;
    f4*       O4 = reinterpret_cast<f4*>(out + OFF_C) + (size_t)grow0 * 256;

    float dacc[16];
    #pragma unroll
    for (int rr = 0; rr < 16; ++rr) dacc[rr] = 0.f;

    #pragma unroll
    for (int rr = 0; rr < 16; ++rr) {
        const float fex = s_fex[w * 16 + rr];
        const float ksc = s_ksc[w * 16 + rr];

        const int base = rr * 256 + lane;
        f4 c0 = __builtin_nontemporal_load(&C4[base]);
        f4 c1 = __builtin_nontemporal_load(&C4[base + 64]);
        f4 c2 = __builtin_nontemporal_load(&C4[base + 128]);
        f4 c3 = __builtin_nontemporal_load(&C4[base + 192]);

        O4[base]       = fex * c0 + ksc * k0;
        O4[base + 64]  = fex * c1 + ksc * k1;
        O4[base + 128] = fex * c2 + ksc * k2;
        O4[base + 192] = fex * c3 + ksc * k3;

        f4 d = c0 * q0 + c1 * q1 + c2 * q2 + c3 * q3;
        dacc[rr] = d.x + d.y + d.z + d.w;
    }

    // 16 independent reduces (ILP) + h stores, once per wave
    float dC[16];
    #pragma unroll
    for (int rr = 0; rr < 16; ++rr) dC[rr] = wave_sum64_dpp(dacc[rr]);
    if (lane == 0) {
        #pragma unroll
        for (int rr = 0; rr < 16; ++rr) {
            const float fex = s_fex[w * 16 + rr];
            const float ksc = s_ksc[w * 16 + rr];
            const float so  = s_so[w * 16 + rr];
            out[OFF_H + grow0 + rr] = so * (fex * dC[rr] + ksc * kqdot);
        }
    }
}

extern "C" void kernel_launch(void* const* d_in, const int* in_sizes, int n_in,
                              void* d_out, int out_size, void* d_ws, size_t ws_size,
                              hipStream_t stream) {
    const float* x = (const float*)d_in[0];
    const float* C = (const float*)d_in[1];
    const float* n = (const float*)d_in[2];
    const float* m = (const float*)d_in[3];
    float* ws  = (float*)d_ws;    // needs 6*65536*4 = 1.5 MB
    float* out = (float*)d_out;

    gemm6_mfma<<<384, 256, 0, stream>>>(
        x,
        (const float*)d_in[4],  (const float*)d_in[5],
        (const float*)d_in[6],  (const float*)d_in[7],
        (const float*)d_in[8],  (const float*)d_in[9],
        (const float*)d_in[10], (const float*)d_in[11],
        (const float*)d_in[12], (const float*)d_in[13],
        (const float*)d_in[14], (const float*)d_in[15],
        ws);
    cupdate11<<<NROW / RPB, 256, 0, stream>>>(C, n, m, ws, out);
}

// Round 16
// 118.548 us; speedup vs baseline: 1.3364x; 1.0250x over previous
//
#include <hip/hip_runtime.h>
#include <hip/hip_bf16.h>
#include <math.h>

#define BATCH 64
#define DIM 1024
#define NROW (BATCH * DIM)        // 65536 rows of C
// d_out layout (floats): h[65536] | C_new[67108864] | n_new[65536] | m_new[65536]
#define OFF_H 0
#define OFF_C 65536
#define OFF_N (65536 + 67108864)
#define OFF_M (OFF_N + 65536)

typedef float f4     __attribute__((ext_vector_type(4)));
typedef float f32x4  __attribute__((ext_vector_type(4)));   // MFMA C/D frag
typedef short bf16x8 __attribute__((ext_vector_type(8)));   // MFMA A/B frag (8 bf16)

// ws layout (floats): pre[6][NROW], gate order 0:q 1:k 2:v 3:i 4:f 5:o

__device__ inline short f2bf(float v) {
    __hip_bfloat16 h = __float2bfloat16(v);   // RNE convert
    short s;
    __builtin_memcpy(&s, &h, 2);
    return s;
}

__device__ inline bf16x8 load_bf8(const float* __restrict__ p) {
    f4 a = *reinterpret_cast<const f4*>(p);
    f4 b = *reinterpret_cast<const f4*>(p + 4);
    bf16x8 r;
    r[0] = f2bf(a.x); r[1] = f2bf(a.y); r[2] = f2bf(a.z); r[3] = f2bf(a.w);
    r[4] = f2bf(b.x); r[5] = f2bf(b.y); r[6] = f2bf(b.z); r[7] = f2bf(b.w);
    return r;
}

__device__ inline int   biti(float f) { int i;   __builtin_memcpy(&i, &f, 4); return i; }
__device__ inline float bitf(int i)   { float f; __builtin_memcpy(&f, &i, 4); return f; }

// Wave-64 sum via DPP (row_shr x4 + row_bcast15 + row_bcast31), wave-uniform
// result from readlane 63. ~6 VALU-latency deps, no LDS.
__device__ inline float wave_sum64_dpp(float x) {
    int t;
    t = __builtin_amdgcn_update_dpp(0, biti(x), 0x111, 0xF, 0xF, true); x += bitf(t);
    t = __builtin_amdgcn_update_dpp(0, biti(x), 0x112, 0xF, 0xF, true); x += bitf(t);
    t = __builtin_amdgcn_update_dpp(0, biti(x), 0x114, 0xF, 0xF, true); x += bitf(t);
    t = __builtin_amdgcn_update_dpp(0, biti(x), 0x118, 0xF, 0xF, true); x += bitf(t);
    t = __builtin_amdgcn_update_dpp(0, biti(x), 0x142, 0xA, 0xF, true); x += bitf(t);
    t = __builtin_amdgcn_update_dpp(0, biti(x), 0x143, 0xC, 0xF, true); x += bitf(t);
    return bitf(__builtin_amdgcn_readlane(biti(x), 63));
}

// ---------------------------------------------------------------------------
// Kernel 1: six GEMMs via bf16 MFMA.
// ---------------------------------------------------------------------------
__global__ __launch_bounds__(256) void gemm6_mfma(
    const float* __restrict__ x,
    const float* __restrict__ Wq, const float* __restrict__ bq,
    const float* __restrict__ Wk, const float* __restrict__ bk,
    const float* __restrict__ Wv, const float* __restrict__ bv,
    const float* __restrict__ Wi, const float* __restrict__ bi,
    const float* __restrict__ Wf, const float* __restrict__ bf_,
    const float* __restrict__ Wo, const float* __restrict__ bo,
    float* __restrict__ pre)
{
    const int bx = blockIdx.x;
    const int g  = bx >> 6;             // gate
    const int j0 = (bx & 63) << 4;      // 16-col tile
    const float* W; const float* bias;
    switch (g) {
        case 0: W = Wq; bias = bq; break;
        case 1: W = Wk; bias = bk; break;
        case 2: W = Wv; bias = bv; break;
        case 3: W = Wi; bias = bi; break;
        case 4: W = Wf; bias = bf_; break;
        default: W = Wo; bias = bo; break;
    }

    const int wave = threadIdx.x >> 6;
    const int lane = threadIdx.x & 63;
    const int l15  = lane & 15;
    const int kq   = lane >> 4;         // 0..3

    const float* xrow = x + (size_t)(wave * 16 + l15) * DIM + kq * 8;
    const float* wrow = W + (size_t)(j0 + l15) * DIM + kq * 8;

    f32x4 acc0 = {0.f, 0.f, 0.f, 0.f};
    f32x4 acc1 = {0.f, 0.f, 0.f, 0.f};
    #pragma unroll 4
    for (int kt = 0; kt < 32; kt += 2) {
        bf16x8 a0 = load_bf8(xrow + kt * 32);
        bf16x8 b0 = load_bf8(wrow + kt * 32);
        bf16x8 a1 = load_bf8(xrow + kt * 32 + 32);
        bf16x8 b1 = load_bf8(wrow + kt * 32 + 32);
        acc0 = __builtin_amdgcn_mfma_f32_16x16x32_bf16(a0, b0, acc0, 0, 0, 0);
        acc1 = __builtin_amdgcn_mfma_f32_16x16x32_bf16(a1, b1, acc1, 0, 0, 0);
    }
    acc0 += acc1;

    const float bv_ = bias[j0 + l15];           // D col = lane&15
    float* dst = pre + (size_t)g * NROW + (size_t)(wave * 16 + kq * 4) * DIM + j0 + l15;
    #pragma unroll
    for (int r = 0; r < 4; ++r)
        dst[(size_t)r * DIM] = acc0[r] + bv_;   // D row = kq*4 + r
}

// ---------------------------------------------------------------------------
// Kernel 2 (FINAL = v5, session best 118.1 us): copy-shaped stream.
// 2048 blocks (64 b x 32 rows) x 256 thr; wave owns 8 rows.
// nt-LOAD on C (bypass L2/L3 for the read stream: +17 us) + PLAIN stores
// (write-allocate into 256MB L3 absorbs the write stream: nt-store costs
// 11 us). k/q frags register-hoisted; hot loop = {nt-load x4, fma,
// store x4, dot-fma}; all DPP reduces deferred past the loop; h uses
// batch-level identity dot(C_new,q) = fex*dot(C,q) + ksc*dot(k,q).
// Falsified levers (do not revisit): wave shape, in-loop/LDS reduce,
// nt-store, occupancy (8w/SIMD test R14), RPB=64, two-pass split.
// ---------------------------------------------------------------------------
#define RPB 32   // rows per block
__global__ __launch_bounds__(256) void cupdate5(
    const float* __restrict__ C,
    const float* __restrict__ n_in, const float* __restrict__ m_in,
    const float* __restrict__ ws,
    float* __restrict__ out)
{
    __shared__ float kq[2][DIM];          // k_raw, q  (8 KB)
    __shared__ float s_fex[RPB], s_ksc[RPB], s_so[RPB];

    const int blk  = blockIdx.x;          // 0..2047
    const int b    = blk >> 5;            // batch
    const int rg   = blk & 31;            // row-group
    const int tid  = threadIdx.x;
    const int w    = tid >> 6;
    const int lane = tid & 63;

    // stage k (raw pre_k) and q: 256 f4 each, one f4 per thread
    reinterpret_cast<f4*>(kq[0])[tid] = reinterpret_cast<const f4*>(ws + 1 * NROW + b * DIM)[tid];
    reinterpret_cast<f4*>(kq[1])[tid] = reinterpret_cast<const f4*>(ws + 0 * NROW + b * DIM)[tid];

    // per-row gate scalars + n_new/m_new (32 rows, threads 0..31)
    if (tid < RPB) {
        const int row = b * DIM + rg * RPB + tid;
        const float ip  = ws[3 * NROW + row];
        const float fp_ = ws[4 * NROW + row];
        const float op  = ws[5 * NROW + row];
        const float vp  = ws[2 * NROW + row];
        const float mo  = m_in[row];
        const float mn  = fmaxf(fp_ + mo, ip);
        const float iex = expf(ip - mn);
        const float fex = expf(fp_ + mo - mn);
        s_fex[tid] = fex;
        s_ksc[tid] = iex * vp * 0.03125f;
        s_so[tid]  = 1.f / (1.f + expf(-op));
        out[OFF_N + row] = fex * n_in[row] + iex * ws[1 * NROW + row] * 0.03125f;
        out[OFF_M + row] = mn;
    }
    __syncthreads();

    // hoist k/q fragments to registers (row-invariant)
    const f4* kl = reinterpret_cast<const f4*>(kq[0]);
    const f4* ql = reinterpret_cast<const f4*>(kq[1]);
    f4 k0 = kl[lane],       k1 = kl[lane + 64],
       k2 = kl[lane + 128], k3 = kl[lane + 192];
    f4 q0 = ql[lane],       q1 = ql[lane + 64],
       q2 = ql[lane + 128], q3 = ql[lane + 192];

    // batch-level dot(k_raw, q): once per wave
    f4 pp = k0 * q0 + k1 * q1 + k2 * q2 + k3 * q3;
    const float kqdot = wave_sum64_dpp(pp.x + pp.y + pp.z + pp.w);

    const int grow0 = b * DIM + rg * RPB + w * 8;   // wave's first row
    const f4* C4 = reinterpret_cast<const f4*>(C) + (size_t)grow0 * 256;
    f4*       O4 = reinterpret_cast<f4*>(out + OFF_C) + (size_t)grow0 * 256;

    float dacc[8];
    #pragma unroll
    for (int rr = 0; rr < 8; ++rr) dacc[rr] = 0.f;

    #pragma unroll
    for (int rr = 0; rr < 8; ++rr) {
        const float fex = s_fex[w * 8 + rr];
        const float ksc = s_ksc[w * 8 + rr];

        const int base = rr * 256 + lane;
        f4 c0 = __builtin_nontemporal_load(&C4[base]);
        f4 c1 = __builtin_nontemporal_load(&C4[base + 64]);
        f4 c2 = __builtin_nontemporal_load(&C4[base + 128]);
        f4 c3 = __builtin_nontemporal_load(&C4[base + 192]);

        O4[base]       = fex * c0 + ksc * k0;
        O4[base + 64]  = fex * c1 + ksc * k1;
        O4[base + 128] = fex * c2 + ksc * k2;
        O4[base + 192] = fex * c3 + ksc * k3;

        f4 d = c0 * q0 + c1 * q1 + c2 * q2 + c3 * q3;
        dacc[rr] = d.x + d.y + d.z + d.w;
    }

    // 8 independent reduces (ILP) + h stores, once per wave
    float dC[8];
    #pragma unroll
    for (int rr = 0; rr < 8; ++rr) dC[rr] = wave_sum64_dpp(dacc[rr]);
    if (lane == 0) {
        #pragma unroll
        for (int rr = 0; rr < 8; ++rr) {
            const float fex = s_fex[w * 8 + rr];
            const float ksc = s_ksc[w * 8 + rr];
            const float so  = s_so[w * 8 + rr];
            out[OFF_H + grow0 + rr] = so * (fex * dC[rr] + ksc * kqdot);
        }
    }
}

extern "C" void kernel_launch(void* const* d_in, const int* in_sizes, int n_in,
                              void* d_out, int out_size, void* d_ws, size_t ws_size,
                              hipStream_t stream) {
    const float* x = (const float*)d_in[0];
    const float* C = (const float*)d_in[1];
    const float* n = (const float*)d_in[2];
    const float* m = (const float*)d_in[3];
    float* ws  = (float*)d_ws;    // needs 6*65536*4 = 1.5 MB
    float* out = (float*)d_out;

    gemm6_mfma<<<384, 256, 0, stream>>>(
        x,
        (const float*)d_in[4],  (const float*)d_in[5],
        (const float*)d_in[6],  (const float*)d_in[7],
        (const float*)d_in[8],  (const float*)d_in[9],
        (const float*)d_in[10], (const float*)d_in[11],
        (const float*)d_in[12], (const float*)d_in[13],
        (const float*)d_in[14], (const float*)d_in[15],
        ws);
    cupdate5<<<2048, 256, 0, stream>>>(C, n, m, ws, out);
}